// Round 12
// baseline (366.647 us; speedup 1.0000x reference)
//
#include <hip/hip_runtime.h>
#include <cstdint>

#define HW  128
#define NCH 256
#define NOC 18      // G*K*K
#define PLANE (HW * HW)
#define EPSBN 1e-5f

typedef __attribute__((ext_vector_type(8)))  short bf16x8;
typedef __attribute__((ext_vector_type(16))) float f32x16;

__device__ __forceinline__ unsigned short f2bf(float f) {
    union { float f; uint32_t u; } c; c.f = f;
    uint32_t u = c.u;
    uint32_t r = u + 0x7FFFu + ((u >> 16) & 1u);   // RNE
    return (unsigned short)(r >> 16);
}

// swizzled LDS byte offset for tile [slot(4)][px(130)][ic(32)] bf16
// (R6's layout: px stride 64 B; XOR spreads b128 reads over banks)
__device__ __forceinline__ int lds_off(int slot, int px, int ic) {
    int b = ((slot * 130 + px) * 32 + ic) * 2;
    return b ^ ((px & 6) << 3);
}

// ------------- Kernel W: pack weights -> wB[tap][ic>>3][oc(32 pad)][ic&7] bf16
__global__ __launch_bounds__(256) void pasa_wprep(
    const float* __restrict__ w, unsigned short* __restrict__ wB)
{
    int idx = blockIdx.x * 256 + threadIdx.x;      // 9*32*32*8 = 73728
    int icl = idx & 7;
    int oc  = (idx >> 3) & 31;
    int icb = (idx >> 8) & 31;
    int tap = idx >> 13;
    int ic  = icb * 8 + icl;
    float v = (oc < NOC) ? w[((size_t)oc * NCH + ic) * 9 + tap] : 0.0f;
    wB[idx] = f2bf(v);
}

// ------------- Kernel A: K-split implicit-GEMM conv (partial sums) ---------
// grid 1024 = 8 n x 64 row-pairs x 2 K-halves. Block 512 thr = 8 waves,
// R5/R6 staging (scalar 4B loads, 8-ic batches), chunk=32 -> LDS 33.3 KB,
// 4 blocks/CU = 8 waves/SIMD. Epilogue: raw fp32 partial store.
__global__ __launch_bounds__(512, 8) void pasa_conv_part(
    const float* __restrict__ x, const unsigned short* __restrict__ wB,
    float* __restrict__ partial)
{
    __shared__ __align__(16) char lds[4 * 130 * 32 * 2];   // 33280 B

    int flat = blockIdx.x;                 // [0,1024)
    int nf   = (flat & 7) * 128 + (flat >> 3);  // XCD owns one image
    const int n  = nf >> 7;
    const int h  = (nf >> 6) & 1;          // K-half: ic 128*h .. 128*h+127
    const int y0 = (nf & 63) * 2;

    const int tid  = threadIdx.x;
    const int lane = tid & 63;
    const int wv   = tid >> 6;             // wave 0..7
    const int m    = lane & 31;            // MFMA col (pixel in tile)
    const int hi   = lane >> 5;            // k-half-of-16 selector

    const int team = tid >> 7;             // 0..3 -> LDS slot
    const int p128 = tid & 127;            // global px
    int grow;
    if      (team == 0) grow = (y0 == 0) ? 1 : y0 - 1;
    else if (team == 1) grow = y0;
    else if (team == 2) grow = y0 + 1;
    else                grow = (y0 + 1 == HW - 1) ? HW - 2 : y0 + 2;

    const float* xrow = x + (size_t)n * NCH * PLANE + (size_t)grow * HW;

    const int out_row = wv >> 2;
    const int px_tile = (wv & 3) * 32;

    f32x16 acc;
    #pragma unroll
    for (int i = 0; i < 16; ++i) acc[i] = 0.0f;

    for (int chunk = 0; chunk < 4; ++chunk) {
        const int icg0 = h * 128 + chunk * 32;
        // ---- stage 32 ic x 4 rows x 130 px (bf16, swizzled) ----
        #pragma unroll
        for (int it = 0; it < 4; ++it) {
            const int ic = icg0 + it * 8;
            float v[8];
            #pragma unroll
            for (int i = 0; i < 8; ++i)
                v[i] = xrow[(size_t)(ic + i) * PLANE + p128];
            int4 d;
            d.x = (uint32_t)f2bf(v[0]) | ((uint32_t)f2bf(v[1]) << 16);
            d.y = (uint32_t)f2bf(v[2]) | ((uint32_t)f2bf(v[3]) << 16);
            d.z = (uint32_t)f2bf(v[4]) | ((uint32_t)f2bf(v[5]) << 16);
            d.w = (uint32_t)f2bf(v[6]) | ((uint32_t)f2bf(v[7]) << 16);
            *(int4*)(lds + lds_off(team, p128 + 1, it * 8)) = d;
            if (p128 == 0) {               // left halo: reflect px=1
                float hh[8];
                #pragma unroll
                for (int i = 0; i < 8; ++i)
                    hh[i] = xrow[(size_t)(ic + i) * PLANE + 1];
                int4 e;
                e.x = (uint32_t)f2bf(hh[0]) | ((uint32_t)f2bf(hh[1]) << 16);
                e.y = (uint32_t)f2bf(hh[2]) | ((uint32_t)f2bf(hh[3]) << 16);
                e.z = (uint32_t)f2bf(hh[4]) | ((uint32_t)f2bf(hh[5]) << 16);
                e.w = (uint32_t)f2bf(hh[6]) | ((uint32_t)f2bf(hh[7]) << 16);
                *(int4*)(lds + lds_off(team, 0, it * 8)) = e;
            }
            if (p128 == 127) {             // right halo: reflect px=126
                float hh[8];
                #pragma unroll
                for (int i = 0; i < 8; ++i)
                    hh[i] = xrow[(size_t)(ic + i) * PLANE + 126];
                int4 e;
                e.x = (uint32_t)f2bf(hh[0]) | ((uint32_t)f2bf(hh[1]) << 16);
                e.y = (uint32_t)f2bf(hh[2]) | ((uint32_t)f2bf(hh[3]) << 16);
                e.z = (uint32_t)f2bf(hh[4]) | ((uint32_t)f2bf(hh[5]) << 16);
                e.w = (uint32_t)f2bf(hh[6]) | ((uint32_t)f2bf(hh[7]) << 16);
                *(int4*)(lds + lds_off(team, 129, it * 8)) = e;
            }
        }
        __syncthreads();
        // ---- MFMA: 9 taps x 2 k-steps, D = W·X ----
        #pragma unroll
        for (int tap = 0; tap < 9; ++tap) {
            const int dy = tap / 3;
            const int dx = tap % 3 - 1;
            const int slot = out_row + dy;
            const int apx  = px_tile + m + 1 + dx;
            #pragma unroll
            for (int ks = 0; ks < 2; ++ks) {
                const int k0 = ks * 16;
                bf16x8 a = *(const bf16x8*)(lds + lds_off(slot, apx, k0 + hi * 8));
                bf16x8 b = *(const bf16x8*)(wB +
                    (((size_t)tap * 32 + ((icg0 + k0) >> 3) + hi) * 32 + m) * 8);
                acc = __builtin_amdgcn_mfma_f32_32x32x16_bf16(b, a, acc, 0, 0, 0);
            }
        }
        __syncthreads();
    }

    // ---- epilogue: raw partial store [h][n][oc][y][px] ----
    // C/D layout: col(px)=lane&31, row(oc)=(r&3)+8*(r>>2)+4*hi
    float* po = partial + ((size_t)(h * 8 + n) * NOC) * PLANE
              + (size_t)(y0 + out_row) * HW + px_tile + m;
    #pragma unroll
    for (int r = 0; r < 16; ++r) {
        int oc = (r & 3) + 8 * (r >> 2) + 4 * hi;
        if (oc < NOC) po[(size_t)oc * PLANE] = acc[r];
    }
}

// ------------- Kernel A2: reduce halves + BN + softmax ---------------------
// grid 1024 (n,y), 128 thr (px)
__global__ __launch_bounds__(128) void pasa_reduce_softmax(
    const float* __restrict__ partial,
    const float* __restrict__ gamma, const float* __restrict__ beta,
    const float* __restrict__ rmean, const float* __restrict__ rvar,
    float* __restrict__ sigma)
{
    int flat = blockIdx.x;                   // [0,1024)
    int nf   = (flat & 7) * 128 + (flat >> 3);
    const int n = nf >> 7;
    const int y = nf & 127;
    const int px = threadIdx.x;

    const size_t off = (size_t)y * HW + px;
    const float* p0 = partial + ((size_t)n * NOC) * PLANE + off;
    const float* p1 = partial + ((size_t)(8 + n) * NOC) * PLANE + off;

    float vals[NOC];
    float mx = -3.0e38f;
    #pragma unroll
    for (int oc = 0; oc < NOC; ++oc) {
        float s  = p0[(size_t)oc * PLANE] + p1[(size_t)oc * PLANE];
        float sc = gamma[oc] * rsqrtf(rvar[oc] + EPSBN);
        float b  = beta[oc] - rmean[oc] * sc;
        float t  = fmaf(s, sc, b);
        vals[oc] = t;
        mx = fmaxf(mx, t);
    }
    float ssum = 0.0f;
    #pragma unroll
    for (int oc = 0; oc < NOC; ++oc) { vals[oc] = __expf(vals[oc] - mx); ssum += vals[oc]; }
    const float inv = 1.0f / ssum;

    float* so = sigma + (size_t)n * NOC * PLANE + off;
    #pragma unroll
    for (int oc = 0; oc < NOC; ++oc)
        so[(size_t)oc * PLANE] = vals[oc] * inv;
}

// ------------- Kernel B: pooling with explicit 2-deep channel pipeline -----
struct Ld9 {
    float a0, a1, b0, b1, c0, c1;
    float4 ma, mb, mc;
};

__global__ __launch_bounds__(256, 4) void pasa_pool(
    const float* __restrict__ x, const float* __restrict__ sigma,
    float* __restrict__ out)
{
    int flat = blockIdx.x;                 // [0,2048)
    int nf   = (flat & 7) * 256 + (flat >> 3);   // XCD owns one image
    const int n       = nf >> 8;
    const int chsplit = (nf >> 5) & 7;
    const int yq      = nf & 31;

    const int q = threadIdx.x & 31;
    const int r = (threadIdx.x >> 5) & 3;
    const int s = threadIdx.x >> 7;        // group 0/1

    const int y   = yq * 4 + r;
    const int px0 = q * 4;

    const int ym = (y == 0)      ? 1      : y - 1;
    const int yp = (y == HW - 1) ? HW - 2 : y + 1;
    const int lx = (px0 == 0)        ? 1      : px0 - 1;
    const int rx = (px0 + 4 > HW - 1)? HW - 2 : px0 + 4;

    const size_t ymO = (size_t)ym * HW;
    const size_t yO  = (size_t)y  * HW;
    const size_t ypO = (size_t)yp * HW;

    const float* sg = sigma + ((size_t)n * NOC + s * 9) * PLANE
                            + (size_t)y * HW + px0;
    float sgv[9][4];
    #pragma unroll
    for (int k = 0; k < 9; ++k) {
        float4 tt = *(const float4*)(sg + (size_t)k * PLANE);
        sgv[k][0] = tt.x; sgv[k][1] = tt.y; sgv[k][2] = tt.z; sgv[k][3] = tt.w;
    }

    const int c0 = s * 128 + chsplit * 16;
    const float* xn = x + (size_t)n * NCH * PLANE;
    float*       on = out + (size_t)n * NCH * PLANE;

#define LOAD9(ch, L) do {                                               \
        const float* xcp = xn + (size_t)(ch) * PLANE;                   \
        (L).a0 = xcp[ymO + lx];                                         \
        (L).ma = *(const float4*)(xcp + ymO + px0);                     \
        (L).a1 = xcp[ymO + rx];                                         \
        (L).b0 = xcp[yO + lx];                                          \
        (L).mb = *(const float4*)(xcp + yO + px0);                      \
        (L).b1 = xcp[yO + rx];                                          \
        (L).c0 = xcp[ypO + lx];                                         \
        (L).mc = *(const float4*)(xcp + ypO + px0);                     \
        (L).c1 = xcp[ypO + rx];                                         \
    } while (0)

#define FMASTORE(ch, L) do {                                            \
        float ov[4] = {0.f, 0.f, 0.f, 0.f};                             \
        {                                                               \
            float wvv[6] = {(L).a0, (L).ma.x, (L).ma.y, (L).ma.z, (L).ma.w, (L).a1}; \
            _Pragma("unroll") for (int j = 0; j < 4; ++j)               \
                _Pragma("unroll") for (int dx = 0; dx < 3; ++dx)        \
                    ov[j] = fmaf(wvv[j + dx], sgv[dx][j], ov[j]);       \
        }                                                               \
        {                                                               \
            float wvv[6] = {(L).b0, (L).mb.x, (L).mb.y, (L).mb.z, (L).mb.w, (L).b1}; \
            _Pragma("unroll") for (int j = 0; j < 4; ++j)               \
                _Pragma("unroll") for (int dx = 0; dx < 3; ++dx)        \
                    ov[j] = fmaf(wvv[j + dx], sgv[3 + dx][j], ov[j]);   \
        }                                                               \
        {                                                               \
            float wvv[6] = {(L).c0, (L).mc.x, (L).mc.y, (L).mc.z, (L).mc.w, (L).c1}; \
            _Pragma("unroll") for (int j = 0; j < 4; ++j)               \
                _Pragma("unroll") for (int dx = 0; dx < 3; ++dx)        \
                    ov[j] = fmaf(wvv[j + dx], sgv[6 + dx][j], ov[j]);   \
        }                                                               \
        float4 o4 = { ov[0], ov[1], ov[2], ov[3] };                     \
        *(float4*)(on + (size_t)(ch) * PLANE + yO + px0) = o4;          \
    } while (0)

    Ld9 A, B;
    LOAD9(c0, A);
    #pragma unroll
    for (int cc = 0; cc < 16; cc += 2) {
        LOAD9(c0 + cc + 1, B);
        FMASTORE(c0 + cc, A);
        if (cc + 2 < 16) LOAD9(c0 + cc + 2, A);
        FMASTORE(c0 + cc + 1, B);
    }
#undef LOAD9
#undef FMASTORE
}

extern "C" void kernel_launch(void* const* d_in, const int* in_sizes, int n_in,
                              void* d_out, int out_size, void* d_ws, size_t ws_size,
                              hipStream_t stream) {
    const float* x     = (const float*)d_in[0];
    const float* w     = (const float*)d_in[1];
    const float* gamma = (const float*)d_in[2];
    const float* beta  = (const float*)d_in[3];
    const float* rmean = (const float*)d_in[4];
    const float* rvar  = (const float*)d_in[5];
    float* out   = (float*)d_out;
    float* sigma = (float*)d_ws;                 // 8*18*16384*4 = 9.44 MB

    // scratch in d_out (pool fully overwrites d_out last):
    //   partial: 2*8*18*16384 fp32 = 18.9 MB at offset 0
    //   wB:      147 KB at float-offset 16M (64 MB)
    float* partial = out;
    unsigned short* wB = (unsigned short*)(out + (size_t)16 * 1024 * 1024);

    pasa_wprep<<<dim3(288), dim3(256), 0, stream>>>(w, wB);
    pasa_conv_part<<<dim3(1024), dim3(512), 0, stream>>>(x, wB, partial);
    pasa_reduce_softmax<<<dim3(1024), dim3(128), 0, stream>>>(
        partial, gamma, beta, rmean, rvar, sigma);
    pasa_pool<<<dim3(2048), dim3(256), 0, stream>>>(x, sigma, out);
}

// Round 13
// 138.173 us; speedup vs baseline: 2.6535x; 2.6535x over previous
//
#include <hip/hip_runtime.h>
#include <cstdint>

#define HW  128
#define NCH 256
#define NOC 18      // G*K*K
#define PLANE (HW * HW)
#define EPSBN 1e-5f

typedef __attribute__((ext_vector_type(8)))  short bf16x8;
typedef __attribute__((ext_vector_type(16))) float f32x16;

__device__ __forceinline__ unsigned short f2bf(float f) {
    union { float f; uint32_t u; } c; c.f = f;
    uint32_t u = c.u;
    uint32_t r = u + 0x7FFFu + ((u >> 16) & 1u);   // RNE
    return (unsigned short)(r >> 16);
}

__device__ __forceinline__ int4 pack8(const float* v) {
    int4 d;
    d.x = (uint32_t)f2bf(v[0]) | ((uint32_t)f2bf(v[1]) << 16);
    d.y = (uint32_t)f2bf(v[2]) | ((uint32_t)f2bf(v[3]) << 16);
    d.z = (uint32_t)f2bf(v[4]) | ((uint32_t)f2bf(v[5]) << 16);
    d.w = (uint32_t)f2bf(v[6]) | ((uint32_t)f2bf(v[7]) << 16);
    return d;
}

// double-buffered swizzled LDS: [buf(2)][slot(4)][px(130)][ic(32)] bf16
__device__ __forceinline__ int lds_off(int buf, int slot, int px, int ic) {
    int b = ((((buf << 2) + slot) * 130 + px) * 32 + ic) * 2;
    return b ^ ((px & 6) << 3);
}

// ------------- Kernel W: pack weights -> wB[tap][ic>>3][oc(32 pad)][ic&7] bf16
__global__ __launch_bounds__(256) void pasa_wprep(
    const float* __restrict__ w, unsigned short* __restrict__ wB)
{
    int idx = blockIdx.x * 256 + threadIdx.x;      // 9*32*32*8 = 73728
    int icl = idx & 7;
    int oc  = (idx >> 3) & 31;
    int icb = (idx >> 8) & 31;
    int tap = idx >> 13;
    int ic  = icb * 8 + icl;
    float v = (oc < NOC) ? w[((size_t)oc * NCH + ic) * 9 + tap] : 0.0f;
    wB[idx] = f2bf(v);
}

// ------------- Kernel A: dbuf implicit-GEMM conv + BN + softmax (fused) ----
// R5 geometry (512 blocks, 512 thr, 2 rows x 128 px, 2 blocks/CU) but
// chunk=32 with double-buffered LDS and ONE barrier per chunk:
//   [loads c+1] [MFMA c] [pack+write buf^1] [barrier]
// so global-load latency hides under MFMA instead of being exposed at pack.
__global__ __launch_bounds__(512, 4) void pasa_conv_mfma(
    const float* __restrict__ x, const unsigned short* __restrict__ wB,
    const float* __restrict__ gamma, const float* __restrict__ beta,
    const float* __restrict__ rmean, const float* __restrict__ rvar,
    float* __restrict__ sigma)
{
    __shared__ __align__(16) char lds[2 * 4 * 130 * 32 * 2];   // 66560 B

    int flat = blockIdx.x;                 // [0,512)
    int nf   = (flat & 7) * 64 + (flat >> 3);  // XCD gets one image
    const int n  = nf >> 6;
    const int y0 = (nf & 63) * 2;

    const int tid  = threadIdx.x;
    const int lane = tid & 63;
    const int wv   = tid >> 6;             // wave 0..7
    const int m    = lane & 31;            // MFMA col (pixel in tile)
    const int hi   = lane >> 5;            // k-half selector

    const int team = tid >> 7;             // 0..3 -> LDS row slot
    const int p128 = tid & 127;            // global px staged by this thread
    int grow;                              // staged row (reflect)
    if      (team == 0) grow = (y0 == 0) ? 1 : y0 - 1;
    else if (team == 1) grow = y0;
    else if (team == 2) grow = y0 + 1;
    else                grow = (y0 + 1 == HW - 1) ? HW - 2 : y0 + 2;

    const float* xrow = x + (size_t)n * NCH * PLANE + (size_t)grow * HW;

    const int out_row = wv >> 2;
    const int px_tile = (wv & 3) * 32;

    f32x16 acc;
    #pragma unroll
    for (int i = 0; i < 16; ++i) acc[i] = 0.0f;

    // ---- prologue: stage chunk 0 into buf 0 ----
    {
        float s0[8], s1[8], s2[8], s3[8];
        #pragma unroll
        for (int i = 0; i < 8; ++i) s0[i] = xrow[(size_t)(i)      * PLANE + p128];
        #pragma unroll
        for (int i = 0; i < 8; ++i) s1[i] = xrow[(size_t)(8 + i)  * PLANE + p128];
        #pragma unroll
        for (int i = 0; i < 8; ++i) s2[i] = xrow[(size_t)(16 + i) * PLANE + p128];
        #pragma unroll
        for (int i = 0; i < 8; ++i) s3[i] = xrow[(size_t)(24 + i) * PLANE + p128];
        int4 d0 = pack8(s0), d1 = pack8(s1), d2 = pack8(s2), d3 = pack8(s3);
        *(int4*)(lds + lds_off(0, team, p128 + 1, 0))  = d0;
        *(int4*)(lds + lds_off(0, team, p128 + 1, 8))  = d1;
        *(int4*)(lds + lds_off(0, team, p128 + 1, 16)) = d2;
        *(int4*)(lds + lds_off(0, team, p128 + 1, 24)) = d3;
        if (p128 == 1) {                   // left halo slot 0 = gpx 1
            *(int4*)(lds + lds_off(0, team, 0, 0))  = d0;
            *(int4*)(lds + lds_off(0, team, 0, 8))  = d1;
            *(int4*)(lds + lds_off(0, team, 0, 16)) = d2;
            *(int4*)(lds + lds_off(0, team, 0, 24)) = d3;
        }
        if (p128 == 126) {                 // right halo slot 129 = gpx 126
            *(int4*)(lds + lds_off(0, team, 129, 0))  = d0;
            *(int4*)(lds + lds_off(0, team, 129, 8))  = d1;
            *(int4*)(lds + lds_off(0, team, 129, 16)) = d2;
            *(int4*)(lds + lds_off(0, team, 129, 24)) = d3;
        }
    }
    __syncthreads();

    for (int c = 0; c < 8; ++c) {
        const int cb = c & 1;
        const bool more = (c < 7);
        // ---- issue next chunk's loads (fly under the MFMAs) ----
        float s0[8], s1[8], s2[8], s3[8];
        if (more) {
            const int icg = (c + 1) * 32;
            #pragma unroll
            for (int i = 0; i < 8; ++i) s0[i] = xrow[(size_t)(icg + i)      * PLANE + p128];
            #pragma unroll
            for (int i = 0; i < 8; ++i) s1[i] = xrow[(size_t)(icg + 8 + i)  * PLANE + p128];
            #pragma unroll
            for (int i = 0; i < 8; ++i) s2[i] = xrow[(size_t)(icg + 16 + i) * PLANE + p128];
            #pragma unroll
            for (int i = 0; i < 8; ++i) s3[i] = xrow[(size_t)(icg + 24 + i) * PLANE + p128];
        }
        // ---- MFMA: 9 taps x 2 k-steps on chunk c ----
        #pragma unroll
        for (int tap = 0; tap < 9; ++tap) {
            const int dy = tap / 3;
            const int dx = tap % 3 - 1;
            const int slot = out_row + dy;
            const int apx  = px_tile + m + 1 + dx;
            #pragma unroll
            for (int ks = 0; ks < 2; ++ks) {
                bf16x8 a = *(const bf16x8*)(lds + lds_off(cb, slot, apx, ks * 16 + hi * 8));
                bf16x8 b = *(const bf16x8*)(wB +
                    (((size_t)tap * 32 + c * 4 + ks * 2 + hi) * 32 + m) * 8);
                acc = __builtin_amdgcn_mfma_f32_32x32x16_bf16(b, a, acc, 0, 0, 0);
            }
        }
        // ---- pack + write next chunk into the other buffer ----
        if (more) {
            const int tb = cb ^ 1;
            int4 d0 = pack8(s0), d1 = pack8(s1), d2 = pack8(s2), d3 = pack8(s3);
            *(int4*)(lds + lds_off(tb, team, p128 + 1, 0))  = d0;
            *(int4*)(lds + lds_off(tb, team, p128 + 1, 8))  = d1;
            *(int4*)(lds + lds_off(tb, team, p128 + 1, 16)) = d2;
            *(int4*)(lds + lds_off(tb, team, p128 + 1, 24)) = d3;
            if (p128 == 1) {
                *(int4*)(lds + lds_off(tb, team, 0, 0))  = d0;
                *(int4*)(lds + lds_off(tb, team, 0, 8))  = d1;
                *(int4*)(lds + lds_off(tb, team, 0, 16)) = d2;
                *(int4*)(lds + lds_off(tb, team, 0, 24)) = d3;
            }
            if (p128 == 126) {
                *(int4*)(lds + lds_off(tb, team, 129, 0))  = d0;
                *(int4*)(lds + lds_off(tb, team, 129, 8))  = d1;
                *(int4*)(lds + lds_off(tb, team, 129, 16)) = d2;
                *(int4*)(lds + lds_off(tb, team, 129, 24)) = d3;
            }
        }
        __syncthreads();
    }

    // ---- epilogue: BN + softmax over 18 channels, write sigma ----
    // C/D layout: col(px)=lane&31, row(oc)=(r&3)+8*(r>>2)+4*hi
    float vals[16];
    float mx = -3.0e38f;
    #pragma unroll
    for (int r = 0; r < 16; ++r) {
        int oc = (r & 3) + 8 * (r >> 2) + 4 * hi;
        float v = -3.0e38f;
        if (oc < NOC) {
            float sc = gamma[oc] * rsqrtf(rvar[oc] + EPSBN);
            float b  = beta[oc] - rmean[oc] * sc;
            v = fmaf(acc[r], sc, b);
        }
        vals[r] = v;
        mx = fmaxf(mx, v);
    }
    mx = fmaxf(mx, __shfl_xor(mx, 32));
    float s = 0.0f;
    #pragma unroll
    for (int r = 0; r < 16; ++r) {
        int oc = (r & 3) + 8 * (r >> 2) + 4 * hi;
        float e = (oc < NOC) ? __expf(vals[r] - mx) : 0.0f;
        vals[r] = e;
        s += e;
    }
    s += __shfl_xor(s, 32);
    const float inv = 1.0f / s;

    float* so = sigma + (size_t)n * NOC * PLANE
              + (size_t)(y0 + out_row) * HW + px_tile + m;
    #pragma unroll
    for (int r = 0; r < 16; ++r) {
        int oc = (r & 3) + 8 * (r >> 2) + 4 * hi;
        if (oc < NOC) so[(size_t)oc * PLANE] = vals[r] * inv;
    }
}

// ------------- Kernel B: pooling with explicit 2-deep channel pipeline -----
struct Ld9 {
    float a0, a1, b0, b1, c0, c1;
    float4 ma, mb, mc;
};

__global__ __launch_bounds__(256, 4) void pasa_pool(
    const float* __restrict__ x, const float* __restrict__ sigma,
    float* __restrict__ out)
{
    int flat = blockIdx.x;                 // [0,2048)
    int nf   = (flat & 7) * 256 + (flat >> 3);   // XCD owns one image
    const int n       = nf >> 8;
    const int chsplit = (nf >> 5) & 7;
    const int yq      = nf & 31;

    const int q = threadIdx.x & 31;
    const int r = (threadIdx.x >> 5) & 3;
    const int s = threadIdx.x >> 7;        // group 0/1

    const int y   = yq * 4 + r;
    const int px0 = q * 4;

    const int ym = (y == 0)      ? 1      : y - 1;
    const int yp = (y == HW - 1) ? HW - 2 : y + 1;
    const int lx = (px0 == 0)        ? 1      : px0 - 1;
    const int rx = (px0 + 4 > HW - 1)? HW - 2 : px0 + 4;

    const size_t ymO = (size_t)ym * HW;
    const size_t yO  = (size_t)y  * HW;
    const size_t ypO = (size_t)yp * HW;

    const float* sg = sigma + ((size_t)n * NOC + s * 9) * PLANE
                            + (size_t)y * HW + px0;
    float sgv[9][4];
    #pragma unroll
    for (int k = 0; k < 9; ++k) {
        float4 tt = *(const float4*)(sg + (size_t)k * PLANE);
        sgv[k][0] = tt.x; sgv[k][1] = tt.y; sgv[k][2] = tt.z; sgv[k][3] = tt.w;
    }

    const int c0 = s * 128 + chsplit * 16;
    const float* xn = x + (size_t)n * NCH * PLANE;
    float*       on = out + (size_t)n * NCH * PLANE;

#define LOAD9(ch, L) do {                                               \
        const float* xcp = xn + (size_t)(ch) * PLANE;                   \
        (L).a0 = xcp[ymO + lx];                                         \
        (L).ma = *(const float4*)(xcp + ymO + px0);                     \
        (L).a1 = xcp[ymO + rx];                                         \
        (L).b0 = xcp[yO + lx];                                          \
        (L).mb = *(const float4*)(xcp + yO + px0);                      \
        (L).b1 = xcp[yO + rx];                                          \
        (L).c0 = xcp[ypO + lx];                                         \
        (L).mc = *(const float4*)(xcp + ypO + px0);                     \
        (L).c1 = xcp[ypO + rx];                                         \
    } while (0)

#define FMASTORE(ch, L) do {                                            \
        float ov[4] = {0.f, 0.f, 0.f, 0.f};                             \
        {                                                               \
            float wvv[6] = {(L).a0, (L).ma.x, (L).ma.y, (L).ma.z, (L).ma.w, (L).a1}; \
            _Pragma("unroll") for (int j = 0; j < 4; ++j)               \
                _Pragma("unroll") for (int dx = 0; dx < 3; ++dx)        \
                    ov[j] = fmaf(wvv[j + dx], sgv[dx][j], ov[j]);       \
        }                                                               \
        {                                                               \
            float wvv[6] = {(L).b0, (L).mb.x, (L).mb.y, (L).mb.z, (L).mb.w, (L).b1}; \
            _Pragma("unroll") for (int j = 0; j < 4; ++j)               \
                _Pragma("unroll") for (int dx = 0; dx < 3; ++dx)        \
                    ov[j] = fmaf(wvv[j + dx], sgv[3 + dx][j], ov[j]);   \
        }                                                               \
        {                                                               \
            float wvv[6] = {(L).c0, (L).mc.x, (L).mc.y, (L).mc.z, (L).mc.w, (L).c1}; \
            _Pragma("unroll") for (int j = 0; j < 4; ++j)               \
                _Pragma("unroll") for (int dx = 0; dx < 3; ++dx)        \
                    ov[j] = fmaf(wvv[j + dx], sgv[6 + dx][j], ov[j]);   \
        }                                                               \
        float4 o4 = { ov[0], ov[1], ov[2], ov[3] };                     \
        *(float4*)(on + (size_t)(ch) * PLANE + yO + px0) = o4;          \
    } while (0)

    Ld9 A, B;
    LOAD9(c0, A);
    #pragma unroll
    for (int cc = 0; cc < 16; cc += 2) {
        LOAD9(c0 + cc + 1, B);
        FMASTORE(c0 + cc, A);
        if (cc + 2 < 16) LOAD9(c0 + cc + 2, A);
        FMASTORE(c0 + cc + 1, B);
    }
#undef LOAD9
#undef FMASTORE
}

extern "C" void kernel_launch(void* const* d_in, const int* in_sizes, int n_in,
                              void* d_out, int out_size, void* d_ws, size_t ws_size,
                              hipStream_t stream) {
    const float* x     = (const float*)d_in[0];
    const float* w     = (const float*)d_in[1];
    const float* gamma = (const float*)d_in[2];
    const float* beta  = (const float*)d_in[3];
    const float* rmean = (const float*)d_in[4];
    const float* rvar  = (const float*)d_in[5];
    float* out   = (float*)d_out;
    float* sigma = (float*)d_ws;                 // 8*18*16384*4 = 9.44 MB

    // wB scratch in d_out (pool fully overwrites d_out afterwards)
    unsigned short* wB = (unsigned short*)(out + (size_t)16 * 1024 * 1024);

    pasa_wprep<<<dim3(288), dim3(256), 0, stream>>>(w, wB);
    pasa_conv_mfma<<<dim3(512), dim3(512), 0, stream>>>(
        x, wB, gamma, beta, rmean, rvar, sigma);
    pasa_pool<<<dim3(2048), dim3(256), 0, stream>>>(x, sigma, out);
}